// Round 17
// baseline (61.116 us; speedup 1.0000x reference)
//
#include <hip/hip_runtime.h>
#include <math.h>

namespace {
constexpr int RADIUS = 9;
constexpr float EPSV = 1e-5f;
constexpr int N_ = 2, C_ = 64, H_ = 128, W_ = 192;
constexpr int HW  = H_ * W_;            // 24576
constexpr int CHW = C_ * HW;
constexpr size_t OUT1 = (size_t)N_ * 81 * HW;

constexpr int XT = 64, YT = 4;          // spatial tile
constexpr int NIG = 3;                  // i-values per block (wave-partitioned)
constexpr int NT = 768;                 // 12 waves = 3 il x 4 cg
constexpr int NW = 4;                   // c-groups
constexpr int ROUNDS = 16;              // 1 channel / wave / round
constexpr int MROWS = 6;                // invM halo rows = YT + NIG - 1
constexpr int NCH = 19;                 // invM halo chunks per row
constexpr int MCOLS = 76;
constexpr int MAP_SLOTS = MROWS * NCH;  // 114
constexpr int OFF_INVM = 5 * NT * 4;    // 15360 (epilogue reduce overlay first)
constexpr int LDS_F = OFF_INVM + MROWS * MCOLS;   // 15816 floats = 63264 B
}

// ---------------------------------------------------------------------------
// Kernel 1: invM (map channel-norms) + left-edge replicate strip.
//   strip[(n*C+c)*H + y][0..3] = map[n,c,y,0]
// ---------------------------------------------------------------------------
__global__ __launch_bounds__(64)
void norms_kernel(const float* __restrict__ mp,
                  float* __restrict__ invM,
                  float* __restrict__ strip) {
    __shared__ float4 sM[8][8];
    const int tid = threadIdx.x;
    const int cg = tid >> 3;
    const int s  = tid & 7;
    const int q4 = blockIdx.x * 8 + s;
    const int n = q4 / (HW / 4);
    const int pix = (q4 - n * (HW / 4)) * 4;
    const int y = pix / W_;
    const int x = pix - y * W_;
    const float* pm = mp + (size_t)n * CHW + pix;
    const bool e = (x == 0);
    float* sp = strip + ((size_t)(n * C_ + cg * 8) * H_ + y) * 4;

    float4 sm = {0.f, 0.f, 0.f, 0.f};
#pragma unroll
    for (int cc = 0; cc < 8; ++cc) {
        float4 b = *(const float4*)(pm + (size_t)(cg * 8 + cc) * HW);
        sm.x = fmaf(b.x, b.x, sm.x); sm.y = fmaf(b.y, b.y, sm.y);
        sm.z = fmaf(b.z, b.z, sm.z); sm.w = fmaf(b.w, b.w, sm.w);
        if (e) { float4 v = {b.x, b.x, b.x, b.x}; *(float4*)(sp + (size_t)cc * H_ * 4) = v; }
    }
    sM[cg][s] = sm;
    __syncthreads();
    if (tid < 8) {
        float4 b = sM[0][tid];
#pragma unroll
        for (int g = 1; g < 8; ++g) {
            float4 v = sM[g][tid];
            b.x += v.x; b.y += v.y; b.z += v.z; b.w += v.w;
        }
        float4 vm;
        vm.x = 1.f / (sqrtf(b.x) + EPSV); vm.y = 1.f / (sqrtf(b.y) + EPSV);
        vm.z = 1.f / (sqrtf(b.z) + EPSV); vm.w = 1.f / (sqrtf(b.w) + EPSV);
        *(float4*)(invM + (size_t)n * HW + pix) = vm;
    }
}

// ---------------------------------------------------------------------------
// Kernel 2: raw correlation + inline img-norm. No LDS/barriers in main loop;
// per-lane direct global reads. 12 waves = 3 i x 4 cg share one CU's L1:
// img tile read 3x -> L1 hits; map rows overlap 2x across i-waves.
//   dotRaw[p,(i,j)] = sum_c map[c, clamp(p+(i,j)-9)] * img[c, p]
//   out_diss = invI[p]*dotRaw ;  out_cos = 1 - invM[p']*out_diss
// ---------------------------------------------------------------------------
__global__ __launch_bounds__(NT)
void corr_kernel(const float* __restrict__ img,
                 const float* __restrict__ mp,
                 const float* __restrict__ invMg,
                 const float* __restrict__ strip,
                 float* __restrict__ out) {
    __shared__ float smem[LDS_F];

    const int bz = blockIdx.z;             // n*3 + ig
    const int n  = bz / NIG;
    const int ig = bz - n * NIG;
    const int x0 = blockIdx.x * XT;
    const int y0 = blockIdx.y * YT;
    const int tid = threadIdx.x;
    const int w    = tid >> 6;             // 0..11
    const int il   = w >> 2;               // 0..2  (i within group)
    const int cg   = w & 3;                // 0..3  (channel group of 16)
    const int lane = tid & 63;
    const int ty = lane >> 4;              // 0..3
    const int xc = lane & 15;              // 0..15
    const int iOff = NIG * ig + il;
    const int ch0 = cg * 16;
    const int ybase0 = y0 + NIG * ig - RADIUS;   // halo row 0

    const float* imgN = img + (size_t)n * CHW;
    const float* mapN = mp  + (size_t)n * CHW;

    // ---- invM halo (114 float4; epilogue-only, synced by epilogue barrier) ----
    if (tid < MAP_SLOTS) {
        int r = tid / NCH, k = tid - r * NCH;
        int gy = min(max(ybase0 + r, 0), H_ - 1);
        int gxs = x0 - 12 + 4 * k;
        const float* src = invMg + n * HW + (size_t)gy * W_;
        float4 v;
        if (gxs >= 0) v = *(const float4*)(src + gxs);
        else { float s0 = src[0]; v.x = s0; v.y = s0; v.z = s0; v.w = s0; }
        *(float4*)&smem[OFF_INVM + r * MCOLS + 4 * k] = v;
    }

    // ---- per-lane direct-read descriptors (strip for left-OOB chunks) ----
    const int gy = min(max(y0 + ty + iOff - RADIUS, 0), H_ - 1);
    const float* rowp = mapN + (size_t)ch0 * HW + (size_t)gy * W_;
    const float* stripRow = strip + ((size_t)(n * C_ + ch0) * H_ + gy) * 4;
    const float* pd[4]; int sd[4];
#pragma unroll
    for (int d = 0; d < 4; ++d) {
        int gx = x0 + 4 * xc - 12 + 4 * d;
        if (gx < 0) { pd[d] = stripRow; sd[d] = H_ * 4; }
        else        { pd[d] = rowp + gx; sd[d] = HW; }
    }
    const float* pI = imgN + (size_t)ch0 * HW + (size_t)(y0 + ty) * W_ + x0 + 4 * xc;

    float acc[4][RADIUS];
#pragma unroll
    for (int p = 0; p < 4; ++p)
#pragma unroll
        for (int j = 0; j < RADIUS; ++j) acc[p][j] = 0.f;
    float si[4] = {0.f, 0.f, 0.f, 0.f};

    // ---- main loop: pure register dataflow, no LDS, no barriers ----
#pragma unroll 4
    for (int ri = 0; ri < ROUNDS; ++ri) {
        float wreg[16];
        *(float4*)&wreg[0]  = *(const float4*)(pd[0] + (size_t)ri * sd[0]);
        *(float4*)&wreg[4]  = *(const float4*)(pd[1] + (size_t)ri * sd[1]);
        *(float4*)&wreg[8]  = *(const float4*)(pd[2] + (size_t)ri * sd[2]);
        *(float4*)&wreg[12] = *(const float4*)(pd[3] + (size_t)ri * sd[3]);
        const float4 a4 = *(const float4*)(pI + (size_t)ri * HW);
        const float a[4] = {a4.x, a4.y, a4.z, a4.w};
        si[0] = fmaf(a[0], a[0], si[0]);
        si[1] = fmaf(a[1], a[1], si[1]);
        si[2] = fmaf(a[2], a[2], si[2]);
        si[3] = fmaf(a[3], a[3], si[3]);
#pragma unroll
        for (int p = 0; p < 4; ++p)
#pragma unroll
            for (int j = 0; j < RADIUS; ++j)
                acc[p][j] = fmaf(wreg[p + j + 3], a[p], acc[p][j]);
    }

    // ==== epilogue: per-il 4-way c-reduce, SoA float4 layout ====
    __syncthreads();                       // invM halo ready; LDS free
    const int slot = tid;                  // = il*256 + cg*64 + lane
    const int ilBase = il * 256;
    // ---- half 1: j=0..3 + si ----
#pragma unroll
    for (int q = 0; q < 4; ++q) {
        float4 v = {acc[0][q], acc[1][q], acc[2][q], acc[3][q]};
        *(float4*)&smem[(q * NT + slot) * 4] = v;
    }
    { float4 v = {si[0], si[1], si[2], si[3]}; *(float4*)&smem[(4 * NT + slot) * 4] = v; }
    __syncthreads();
    float4 sv = {0.f, 0.f, 0.f, 0.f};
#pragma unroll
    for (int g = 0; g < NW; ++g) {
        float4 v = *(const float4*)&smem[(4 * NT + ilBase + g * 64 + lane) * 4];
        sv.x += v.x; sv.y += v.y; sv.z += v.z; sv.w += v.w;
    }
    float4 vI;
    vI.x = 1.f / (sqrtf(sv.x) + EPSV);
    vI.y = 1.f / (sqrtf(sv.y) + EPSV);
    vI.z = 1.f / (sqrtf(sv.z) + EPSV);
    vI.w = 1.f / (sqrtf(sv.w) + EPSV);

    const int y  = y0 + ty;
    const int xb = x0 + 4 * xc;
    const float* wmRow = &smem[OFF_INVM + (ty + il) * MCOLS + 4 * xc + 3];
    float* ocB = out + (size_t)(n * 81 + iOff * RADIUS) * HW + (size_t)y * W_ + xb;

    {   // cg stores j = cg
        const int j = cg;
        float4 s = {0.f, 0.f, 0.f, 0.f};
#pragma unroll
        for (int g = 0; g < NW; ++g) {
            float4 v = *(const float4*)&smem[(j * NT + ilBase + g * 64 + lane) * 4];
            s.x += v.x; s.y += v.y; s.z += v.z; s.w += v.w;
        }
        float4 vd, vc;
        vd.x = s.x * vI.x; vd.y = s.y * vI.y; vd.z = s.z * vI.z; vd.w = s.w * vI.w;
        vc.x = 1.f - vd.x * wmRow[j + 0];
        vc.y = 1.f - vd.y * wmRow[j + 1];
        vc.z = 1.f - vd.z * wmRow[j + 2];
        vc.w = 1.f - vd.w * wmRow[j + 3];
        *(float4*)(ocB + (size_t)j * HW) = vc;
        *(float4*)(ocB + OUT1 + (size_t)j * HW) = vd;
    }
    __syncthreads();
    // ---- half 2: j=4..8 ----
#pragma unroll
    for (int q = 0; q < 5; ++q) {
        float4 v = {acc[0][q + 4], acc[1][q + 4], acc[2][q + 4], acc[3][q + 4]};
        *(float4*)&smem[(q * NT + slot) * 4] = v;
    }
    __syncthreads();
    {   // cg stores j = 4 + cg
        const int j = 4 + cg;
        float4 s = {0.f, 0.f, 0.f, 0.f};
#pragma unroll
        for (int g = 0; g < NW; ++g) {
            float4 v = *(const float4*)&smem[((j - 4) * NT + ilBase + g * 64 + lane) * 4];
            s.x += v.x; s.y += v.y; s.z += v.z; s.w += v.w;
        }
        float4 vd, vc;
        vd.x = s.x * vI.x; vd.y = s.y * vI.y; vd.z = s.z * vI.z; vd.w = s.w * vI.w;
        vc.x = 1.f - vd.x * wmRow[j + 0];
        vc.y = 1.f - vd.y * wmRow[j + 1];
        vc.z = 1.f - vd.z * wmRow[j + 2];
        vc.w = 1.f - vd.w * wmRow[j + 3];
        *(float4*)(ocB + (size_t)j * HW) = vc;
        *(float4*)(ocB + OUT1 + (size_t)j * HW) = vd;
    }
    if (cg == 0) {                         // cg0 also stores j = 8
        const int j = 8;
        float4 s = {0.f, 0.f, 0.f, 0.f};
#pragma unroll
        for (int g = 0; g < NW; ++g) {
            float4 v = *(const float4*)&smem[(4 * NT + ilBase + g * 64 + lane) * 4];
            s.x += v.x; s.y += v.y; s.z += v.z; s.w += v.w;
        }
        float4 vd, vc;
        vd.x = s.x * vI.x; vd.y = s.y * vI.y; vd.z = s.z * vI.z; vd.w = s.w * vI.w;
        vc.x = 1.f - vd.x * wmRow[j + 0];
        vc.y = 1.f - vd.y * wmRow[j + 1];
        vc.z = 1.f - vd.z * wmRow[j + 2];
        vc.w = 1.f - vd.w * wmRow[j + 3];
        *(float4*)(ocB + (size_t)j * HW) = vc;
        *(float4*)(ocB + OUT1 + (size_t)j * HW) = vd;
    }
}

extern "C" void kernel_launch(void* const* d_in, const int* in_sizes, int n_in,
                              void* d_out, int out_size, void* d_ws, size_t ws_size,
                              hipStream_t stream) {
    const float* img = (const float*)d_in[0];
    const float* mp  = (const float*)d_in[1];
    float* out   = (float*)d_out;
    float* invM  = (float*)d_ws;                  // N_*HW floats
    float* strip = invM + N_ * HW;                // N_*C_*H_*4 floats (512 KB)

    norms_kernel<<<(N_ * HW / 4) / 8, 64, 0, stream>>>(mp, invM, strip);

    // x-tile fastest (R15-proven order); 3 i's folded into each block
    dim3 grid(W_ / XT, H_ / YT, N_ * NIG);        // 3 x 32 x 6 = 576 blocks
    corr_kernel<<<grid, NT, 0, stream>>>(img, mp, invM, strip, out);
}

// Round 18
// 49.888 us; speedup vs baseline: 1.2251x; 1.2251x over previous
//
#include <hip/hip_runtime.h>
#include <math.h>

namespace {
constexpr int RADIUS = 9;
constexpr float EPSV = 1e-5f;
constexpr int N_ = 2, C_ = 64, H_ = 128, W_ = 192;
constexpr int HW  = H_ * W_;            // 24576
constexpr int CHW = C_ * HW;
constexpr size_t OUT1 = (size_t)N_ * 81 * HW;

constexpr int XT = 64, YT = 4;          // spatial tile; i fully in grid.z
constexpr int NT = 256;                 // 4 waves; wave = channel-group of 16
constexpr int NW = 4;
constexpr int ROUNDS = 16;              // 1 channel / wave / round
constexpr int MROWS = 4;
constexpr int NCH = 19;
constexpr int MCOLS = 76;
constexpr int MAP_SLOTS = MROWS * NCH;  // 76
constexpr int OFF_INVM = 5 * 256 * 4;   // 5120 (epilogue reduce overlay first)
constexpr int LDS_F = OFF_INVM + MROWS * MCOLS;   // 5424 floats = 21696 B
}

// ---------------------------------------------------------------------------
// Kernel 1: invM (map channel-norms) + left-edge replicate strip.
// 256 threads = 8 c-groups x 32 q4-pixels; 384 blocks.
// ---------------------------------------------------------------------------
__global__ __launch_bounds__(256)
void norms_kernel(const float* __restrict__ mp,
                  float* __restrict__ invM,
                  float* __restrict__ strip) {
    __shared__ float4 sM[8][32];
    const int tid = threadIdx.x;
    const int cg = tid >> 5;               // 0..7 (8 channels each)
    const int s  = tid & 31;
    const int q4 = blockIdx.x * 32 + s;    // [0, 12288)
    const int n = q4 / (HW / 4);
    const int pix = (q4 - n * (HW / 4)) * 4;
    const int y = pix / W_;
    const int x = pix - y * W_;
    const float* pm = mp + (size_t)n * CHW + pix;
    const bool e = (x == 0);
    float* sp = strip + ((size_t)(n * C_ + cg * 8) * H_ + y) * 4;

    float4 sm = {0.f, 0.f, 0.f, 0.f};
#pragma unroll
    for (int cc = 0; cc < 8; ++cc) {
        float4 b = *(const float4*)(pm + (size_t)(cg * 8 + cc) * HW);
        sm.x = fmaf(b.x, b.x, sm.x); sm.y = fmaf(b.y, b.y, sm.y);
        sm.z = fmaf(b.z, b.z, sm.z); sm.w = fmaf(b.w, b.w, sm.w);
        if (e) { float4 v = {b.x, b.x, b.x, b.x}; *(float4*)(sp + (size_t)cc * H_ * 4) = v; }
    }
    sM[cg][s] = sm;
    __syncthreads();
    if (tid < 32) {
        float4 b = sM[0][tid];
#pragma unroll
        for (int g = 1; g < 8; ++g) {
            float4 v = sM[g][tid];
            b.x += v.x; b.y += v.y; b.z += v.z; b.w += v.w;
        }
        int q4b = blockIdx.x * 32 + tid;
        int nb = q4b / (HW / 4);
        int pixb = (q4b - nb * (HW / 4)) * 4;
        float4 vm;
        vm.x = 1.f / (sqrtf(b.x) + EPSV); vm.y = 1.f / (sqrtf(b.y) + EPSV);
        vm.z = 1.f / (sqrtf(b.z) + EPSV); vm.w = 1.f / (sqrtf(b.w) + EPSV);
        *(float4*)(invM + (size_t)nb * HW + pixb) = vm;
    }
}

// ---------------------------------------------------------------------------
// Kernel 2: raw correlation + inline img-norm. No LDS/barriers in main loop;
// per-lane direct global reads with REGISTER DOUBLE-BUFFER: loads for round
// ri+1 issue before round ri's FMAs (fully unrolled, static buffer names).
//   dotRaw[p,(i,j)] = sum_c map[c, clamp(p+(i,j)-9)] * img[c, p]
//   out_diss = invI[p]*dotRaw ;  out_cos = 1 - invM[p']*out_diss
// ---------------------------------------------------------------------------
#define LOADR(WREG, A4, RI)                                                    \
    do {                                                                       \
        *(float4*)&WREG[0]  = *(const float4*)(pd0 + (size_t)(RI) * sd0);      \
        *(float4*)&WREG[4]  = *(const float4*)(pd1 + (size_t)(RI) * sd1);      \
        *(float4*)&WREG[8]  = *(const float4*)(pd2 + (size_t)(RI) * sd2);      \
        *(float4*)&WREG[12] = *(const float4*)(pd3 + (size_t)(RI) * sd3);      \
        A4 = *(const float4*)(pI + (size_t)(RI) * HW);                         \
    } while (0)

#define COMPUTE(WREG, A4)                                                      \
    do {                                                                       \
        const float a0 = A4.x, a1 = A4.y, a2 = A4.z, a3 = A4.w;                \
        si[0] = fmaf(a0, a0, si[0]);                                           \
        si[1] = fmaf(a1, a1, si[1]);                                           \
        si[2] = fmaf(a2, a2, si[2]);                                           \
        si[3] = fmaf(a3, a3, si[3]);                                           \
        _Pragma("unroll")                                                      \
        for (int j = 0; j < RADIUS; ++j) {                                     \
            acc[0][j] = fmaf(WREG[0 + j + 3], a0, acc[0][j]);                  \
            acc[1][j] = fmaf(WREG[1 + j + 3], a1, acc[1][j]);                  \
            acc[2][j] = fmaf(WREG[2 + j + 3], a2, acc[2][j]);                  \
            acc[3][j] = fmaf(WREG[3 + j + 3], a3, acc[3][j]);                  \
        }                                                                      \
    } while (0)

__global__ __launch_bounds__(NT)
void corr_kernel(const float* __restrict__ img,
                 const float* __restrict__ mp,
                 const float* __restrict__ invMg,
                 const float* __restrict__ strip,
                 float* __restrict__ out) {
    __shared__ float smem[LDS_F];

    const int bz = blockIdx.z;             // n*9 + i
    const int n    = bz / RADIUS;
    const int iOff = bz - n * RADIUS;
    const int x0 = blockIdx.x * XT;
    const int y0 = blockIdx.y * YT;
    const int tid = threadIdx.x;
    const int w    = tid >> 6;             // wave = channel group (16 ch)
    const int lane = tid & 63;
    const int ty = lane >> 4;              // 0..3
    const int xc = lane & 15;              // 0..15
    const int ch0 = w * 16;

    const float* imgN = img + (size_t)n * CHW;
    const float* mapN = mp  + (size_t)n * CHW;

    // ---- invM halo (76 float4; epilogue-only, synced by epilogue barrier) ----
    if (tid < MAP_SLOTS) {
        int r = tid / NCH, k = tid - r * NCH;
        int gy = min(max(y0 + iOff - RADIUS + r, 0), H_ - 1);
        int gxs = x0 - 12 + 4 * k;
        const float* src = invMg + n * HW + (size_t)gy * W_;
        float4 v;
        if (gxs >= 0) v = *(const float4*)(src + gxs);
        else { float s0 = src[0]; v.x = s0; v.y = s0; v.z = s0; v.w = s0; }
        *(float4*)&smem[OFF_INVM + r * MCOLS + 4 * k] = v;
    }

    // ---- per-lane direct-read descriptors (strip for left-OOB chunks) ----
    const int gy = min(max(y0 + ty + iOff - RADIUS, 0), H_ - 1);
    const float* rowp = mapN + (size_t)ch0 * HW + (size_t)gy * W_;
    const float* stripRow = strip + ((size_t)(n * C_ + ch0) * H_ + gy) * 4;
    const float *pd0, *pd1, *pd2, *pd3;
    int sd0, sd1, sd2, sd3;
    {
        int gx0 = x0 + 4 * xc - 12;
        if (gx0 < 0) { pd0 = stripRow; sd0 = H_ * 4; } else { pd0 = rowp + gx0; sd0 = HW; }
        int gx1 = gx0 + 4;
        if (gx1 < 0) { pd1 = stripRow; sd1 = H_ * 4; } else { pd1 = rowp + gx1; sd1 = HW; }
        int gx2 = gx0 + 8;
        if (gx2 < 0) { pd2 = stripRow; sd2 = H_ * 4; } else { pd2 = rowp + gx2; sd2 = HW; }
        int gx3 = gx0 + 12;
        pd3 = rowp + gx3; sd3 = HW;        // gx3 = 4xc >= 0 always
    }
    const float* pI = imgN + (size_t)ch0 * HW + (size_t)(y0 + ty) * W_ + x0 + 4 * xc;

    float acc[4][RADIUS];
#pragma unroll
    for (int p = 0; p < 4; ++p)
#pragma unroll
        for (int j = 0; j < RADIUS; ++j) acc[p][j] = 0.f;
    float si[4] = {0.f, 0.f, 0.f, 0.f};

    // ---- main loop: fully-unrolled register double-buffer ----
    float wregA[16], wregB[16];
    float4 aA, aB;
    LOADR(wregA, aA, 0);
#pragma unroll
    for (int ri = 0; ri < ROUNDS; ++ri) {
        if ((ri & 1) == 0) {
            if (ri + 1 < ROUNDS) LOADR(wregB, aB, ri + 1);
            COMPUTE(wregA, aA);
        } else {
            if (ri + 1 < ROUNDS) LOADR(wregA, aA, ri + 1);
            COMPUTE(wregB, aB);
        }
    }

    // ==== epilogue: 4-way cross-wave reduce, SoA float4 layout ====
    __syncthreads();                       // invM halo ready; LDS free
    const int slot = tid;                  // 0..255
#pragma unroll
    for (int q = 0; q < 4; ++q) {
        float4 v = {acc[0][q], acc[1][q], acc[2][q], acc[3][q]};
        *(float4*)&smem[(q * 256 + slot) * 4] = v;
    }
    { float4 v = {si[0], si[1], si[2], si[3]}; *(float4*)&smem[(4 * 256 + slot) * 4] = v; }
    __syncthreads();
    float4 sv = {0.f, 0.f, 0.f, 0.f};
#pragma unroll
    for (int g = 0; g < NW; ++g) {
        float4 v = *(const float4*)&smem[(4 * 256 + g * 64 + lane) * 4];
        sv.x += v.x; sv.y += v.y; sv.z += v.z; sv.w += v.w;
    }
    float4 vI;
    vI.x = 1.f / (sqrtf(sv.x) + EPSV);
    vI.y = 1.f / (sqrtf(sv.y) + EPSV);
    vI.z = 1.f / (sqrtf(sv.z) + EPSV);
    vI.w = 1.f / (sqrtf(sv.w) + EPSV);

    const int y  = y0 + ty;
    const int xb = x0 + 4 * xc;
    const float* wmRow = &smem[OFF_INVM + ty * MCOLS + 4 * xc + 3];
    float* ocB = out + (size_t)(n * 81 + iOff * RADIUS) * HW + (size_t)y * W_ + xb;

    {   // waves 0..3 store j = w
        const int j = w;
        float4 s = {0.f, 0.f, 0.f, 0.f};
#pragma unroll
        for (int g = 0; g < NW; ++g) {
            float4 v = *(const float4*)&smem[(j * 256 + g * 64 + lane) * 4];
            s.x += v.x; s.y += v.y; s.z += v.z; s.w += v.w;
        }
        float4 vd, vc;
        vd.x = s.x * vI.x; vd.y = s.y * vI.y; vd.z = s.z * vI.z; vd.w = s.w * vI.w;
        vc.x = 1.f - vd.x * wmRow[j + 0];
        vc.y = 1.f - vd.y * wmRow[j + 1];
        vc.z = 1.f - vd.z * wmRow[j + 2];
        vc.w = 1.f - vd.w * wmRow[j + 3];
        *(float4*)(ocB + (size_t)j * HW) = vc;
        *(float4*)(ocB + OUT1 + (size_t)j * HW) = vd;
    }
    __syncthreads();
#pragma unroll
    for (int q = 0; q < 5; ++q) {
        float4 v = {acc[0][q + 4], acc[1][q + 4], acc[2][q + 4], acc[3][q + 4]};
        *(float4*)&smem[(q * 256 + slot) * 4] = v;
    }
    __syncthreads();
    {   // waves 0..3 store j = 4 + w
        const int j = 4 + w;
        float4 s = {0.f, 0.f, 0.f, 0.f};
#pragma unroll
        for (int g = 0; g < NW; ++g) {
            float4 v = *(const float4*)&smem[((j - 4) * 256 + g * 64 + lane) * 4];
            s.x += v.x; s.y += v.y; s.z += v.z; s.w += v.w;
        }
        float4 vd, vc;
        vd.x = s.x * vI.x; vd.y = s.y * vI.y; vd.z = s.z * vI.z; vd.w = s.w * vI.w;
        vc.x = 1.f - vd.x * wmRow[j + 0];
        vc.y = 1.f - vd.y * wmRow[j + 1];
        vc.z = 1.f - vd.z * wmRow[j + 2];
        vc.w = 1.f - vd.w * wmRow[j + 3];
        *(float4*)(ocB + (size_t)j * HW) = vc;
        *(float4*)(ocB + OUT1 + (size_t)j * HW) = vd;
    }
    if (w == 0) {                          // wave 0 also stores j = 8
        const int j = 8;
        float4 s = {0.f, 0.f, 0.f, 0.f};
#pragma unroll
        for (int g = 0; g < NW; ++g) {
            float4 v = *(const float4*)&smem[(4 * 256 + g * 64 + lane) * 4];
            s.x += v.x; s.y += v.y; s.z += v.z; s.w += v.w;
        }
        float4 vd, vc;
        vd.x = s.x * vI.x; vd.y = s.y * vI.y; vd.z = s.z * vI.z; vd.w = s.w * vI.w;
        vc.x = 1.f - vd.x * wmRow[j + 0];
        vc.y = 1.f - vd.y * wmRow[j + 1];
        vc.z = 1.f - vd.z * wmRow[j + 2];
        vc.w = 1.f - vd.w * wmRow[j + 3];
        *(float4*)(ocB + (size_t)j * HW) = vc;
        *(float4*)(ocB + OUT1 + (size_t)j * HW) = vd;
    }
}

extern "C" void kernel_launch(void* const* d_in, const int* in_sizes, int n_in,
                              void* d_out, int out_size, void* d_ws, size_t ws_size,
                              hipStream_t stream) {
    const float* img = (const float*)d_in[0];
    const float* mp  = (const float*)d_in[1];
    float* out   = (float*)d_out;
    float* invM  = (float*)d_ws;                  // N_*HW floats
    float* strip = invM + N_ * HW;                // N_*C_*H_*4 floats (512 KB)

    norms_kernel<<<(N_ * HW / 4) / 32, 256, 0, stream>>>(mp, invM, strip);

    dim3 grid(W_ / XT, H_ / YT, N_ * RADIUS);     // 3 x 32 x 18 = 1728 blocks
    corr_kernel<<<grid, NT, 0, stream>>>(img, mp, invM, strip, out);
}

// Round 19
// 33.045 us; speedup vs baseline: 1.8495x; 1.5097x over previous
//
#include <hip/hip_runtime.h>
#include <math.h>

namespace {
constexpr int RADIUS = 9;
constexpr float EPSV = 1e-5f;
constexpr int N_ = 2, C_ = 64, H_ = 128, W_ = 192;
constexpr int HW  = H_ * W_;            // 24576
constexpr int CHW = C_ * HW;
constexpr size_t OUT1 = (size_t)N_ * 81 * HW;

constexpr int XT = 64, YT = 4;          // spatial tile; i fully in grid.z
constexpr int NT = 256;                 // 4 waves; wave = channel-group of 16
constexpr int NW = 4;
constexpr int ROUNDS = 16;              // 1 channel / wave / round
constexpr int MROWS = 4;
constexpr int NCH = 19;
constexpr int MCOLS = 76;
constexpr int MAP_SLOTS = MROWS * NCH;  // 76
constexpr int OFF_INVM = 5 * 256 * 4;   // 5120 (epilogue reduce overlay first)
constexpr int LDS_F = OFF_INVM + MROWS * MCOLS;   // 5424 floats = 21696 B
}

// ---------------------------------------------------------------------------
// Kernel 1: invM (map channel-norms) + left-edge strips.
//   strip [(n*C+c)*H + y][0..3] = {m0,m0,m0,m0}   (m_k = map[n,c,y,k])
//   strip2[(n*C+c)*H + y][0..3] = {m0,m0,m1,m2}   (window starting at x=-1)
// 256 threads = 8 c-groups x 32 q4-pixels; 384 blocks.
// ---------------------------------------------------------------------------
__global__ __launch_bounds__(256)
void norms_kernel(const float* __restrict__ mp,
                  float* __restrict__ invM,
                  float* __restrict__ strip,
                  float* __restrict__ strip2) {
    __shared__ float4 sM[8][32];
    const int tid = threadIdx.x;
    const int cg = tid >> 5;               // 0..7 (8 channels each)
    const int s  = tid & 31;
    const int q4 = blockIdx.x * 32 + s;    // [0, 12288)
    const int n = q4 / (HW / 4);
    const int pix = (q4 - n * (HW / 4)) * 4;
    const int y = pix / W_;
    const int x = pix - y * W_;
    const float* pm = mp + (size_t)n * CHW + pix;
    const bool e = (x == 0);
    float* sp  = strip  + ((size_t)(n * C_ + cg * 8) * H_ + y) * 4;
    float* sp2 = strip2 + ((size_t)(n * C_ + cg * 8) * H_ + y) * 4;

    float4 sm = {0.f, 0.f, 0.f, 0.f};
#pragma unroll
    for (int cc = 0; cc < 8; ++cc) {
        float4 b = *(const float4*)(pm + (size_t)(cc + 0) * HW + (size_t)cg * 8 * HW);
        sm.x = fmaf(b.x, b.x, sm.x); sm.y = fmaf(b.y, b.y, sm.y);
        sm.z = fmaf(b.z, b.z, sm.z); sm.w = fmaf(b.w, b.w, sm.w);
        if (e) {
            float4 v1 = {b.x, b.x, b.x, b.x};
            float4 v2 = {b.x, b.x, b.y, b.z};
            *(float4*)(sp  + (size_t)cc * H_ * 4) = v1;
            *(float4*)(sp2 + (size_t)cc * H_ * 4) = v2;
        }
    }
    sM[cg][s] = sm;
    __syncthreads();
    if (tid < 32) {
        float4 b = sM[0][tid];
#pragma unroll
        for (int g = 1; g < 8; ++g) {
            float4 v = sM[g][tid];
            b.x += v.x; b.y += v.y; b.z += v.z; b.w += v.w;
        }
        int q4b = blockIdx.x * 32 + tid;
        int nb = q4b / (HW / 4);
        int pixb = (q4b - nb * (HW / 4)) * 4;
        float4 vm;
        vm.x = 1.f / (sqrtf(b.x) + EPSV); vm.y = 1.f / (sqrtf(b.y) + EPSV);
        vm.z = 1.f / (sqrtf(b.z) + EPSV); vm.w = 1.f / (sqrtf(b.w) + EPSV);
        *(float4*)(invM + (size_t)nb * HW + pixb) = vm;
    }
}

// ---------------------------------------------------------------------------
// Kernel 2: raw correlation + inline img-norm. No LDS/barriers in main loop.
// Per round: 3 dword-aligned 16B map loads (exact 12-float window) + 1 img
// float4; 40 FMAs. Left edge = pointer redirect to strip/strip2.
//   dotRaw[p,(i,j)] = sum_c map[c, clamp(p+(i,j)-9)] * img[c, p]
//   out_diss = invI[p]*dotRaw ;  out_cos = 1 - invM[p']*out_diss
// ---------------------------------------------------------------------------
__global__ __launch_bounds__(NT)
void corr_kernel(const float* __restrict__ img,
                 const float* __restrict__ mp,
                 const float* __restrict__ invMg,
                 const float* __restrict__ strip,
                 const float* __restrict__ strip2,
                 float* __restrict__ out) {
    __shared__ float smem[LDS_F];

    const int bz = blockIdx.z;             // n*9 + i
    const int n    = bz / RADIUS;
    const int iOff = bz - n * RADIUS;
    const int x0 = blockIdx.x * XT;
    const int y0 = blockIdx.y * YT;
    const int tid = threadIdx.x;
    const int w    = tid >> 6;             // wave = channel group (16 ch)
    const int lane = tid & 63;
    const int ty = lane >> 4;              // 0..3
    const int xc = lane & 15;              // 0..15
    const int ch0 = w * 16;

    const float* imgN = img + (size_t)n * CHW;
    const float* mapN = mp  + (size_t)n * CHW;

    // ---- invM halo (76 float4; epilogue-only, synced by epilogue barrier) ----
    if (tid < MAP_SLOTS) {
        int r = tid / NCH, k = tid - r * NCH;
        int gy = min(max(y0 + iOff - RADIUS + r, 0), H_ - 1);
        int gxs = x0 - 12 + 4 * k;
        const float* src = invMg + n * HW + (size_t)gy * W_;
        float4 v;
        if (gxs >= 0) v = *(const float4*)(src + gxs);
        else { float s0 = src[0]; v.x = s0; v.y = s0; v.z = s0; v.w = s0; }
        *(float4*)&smem[OFF_INVM + r * MCOLS + 4 * k] = v;
    }

    // ---- per-lane direct-read descriptors (3 chunks, window = x0+4xc-9+[0,12)) ----
    const int gy = min(max(y0 + ty + iOff - RADIUS, 0), H_ - 1);
    const float* rowp = mapN + (size_t)ch0 * HW + (size_t)gy * W_;
    const float* stripRow  = strip  + ((size_t)(n * C_ + ch0) * H_ + gy) * 4;
    const float* stripRow2 = strip2 + ((size_t)(n * C_ + ch0) * H_ + gy) * 4;
    const float *pd0, *pd1, *pd2;
    int sd0, sd1, sd2;
    {
        const int gxb = x0 + 4 * xc - 9;
        if (gxb <= -4)     { pd0 = stripRow;  sd0 = H_ * 4; }
        else if (gxb < 0)  { pd0 = stripRow2; sd0 = H_ * 4; }   // gxb == -1
        else               { pd0 = rowp + gxb; sd0 = HW; }
        const int g1 = gxb + 4;
        if (g1 <= -4)      { pd1 = stripRow;  sd1 = H_ * 4; }
        else if (g1 < 0)   { pd1 = stripRow2; sd1 = H_ * 4; }
        else               { pd1 = rowp + g1;  sd1 = HW; }
        const int g2 = gxb + 8;
        if (g2 < 0)        { pd2 = stripRow2; sd2 = H_ * 4; }   // g2 == -1 only
        else               { pd2 = rowp + g2;  sd2 = HW; }
    }
    const float* pI = imgN + (size_t)ch0 * HW + (size_t)(y0 + ty) * W_ + x0 + 4 * xc;

    float acc[4][RADIUS];
#pragma unroll
    for (int p = 0; p < 4; ++p)
#pragma unroll
        for (int j = 0; j < RADIUS; ++j) acc[p][j] = 0.f;
    float si[4] = {0.f, 0.f, 0.f, 0.f};

    // ---- main loop: pure register dataflow, no LDS, no barriers ----
#pragma unroll 4
    for (int ri = 0; ri < ROUNDS; ++ri) {
        float wreg[12];
        __builtin_memcpy(&wreg[0], pd0 + (size_t)ri * sd0, 16);
        __builtin_memcpy(&wreg[4], pd1 + (size_t)ri * sd1, 16);
        __builtin_memcpy(&wreg[8], pd2 + (size_t)ri * sd2, 16);
        const float4 a4 = *(const float4*)(pI + (size_t)ri * HW);
        const float a[4] = {a4.x, a4.y, a4.z, a4.w};
        si[0] = fmaf(a[0], a[0], si[0]);
        si[1] = fmaf(a[1], a[1], si[1]);
        si[2] = fmaf(a[2], a[2], si[2]);
        si[3] = fmaf(a[3], a[3], si[3]);
#pragma unroll
        for (int p = 0; p < 4; ++p)
#pragma unroll
            for (int j = 0; j < RADIUS; ++j)
                acc[p][j] = fmaf(wreg[p + j], a[p], acc[p][j]);
    }

    // ==== epilogue: 4-way cross-wave reduce, SoA float4 layout ====
    __syncthreads();                       // invM halo ready; LDS free
    const int slot = tid;                  // 0..255
#pragma unroll
    for (int q = 0; q < 4; ++q) {
        float4 v = {acc[0][q], acc[1][q], acc[2][q], acc[3][q]};
        *(float4*)&smem[(q * 256 + slot) * 4] = v;
    }
    { float4 v = {si[0], si[1], si[2], si[3]}; *(float4*)&smem[(4 * 256 + slot) * 4] = v; }
    __syncthreads();
    float4 sv = {0.f, 0.f, 0.f, 0.f};
#pragma unroll
    for (int g = 0; g < NW; ++g) {
        float4 v = *(const float4*)&smem[(4 * 256 + g * 64 + lane) * 4];
        sv.x += v.x; sv.y += v.y; sv.z += v.z; sv.w += v.w;
    }
    float4 vI;
    vI.x = 1.f / (sqrtf(sv.x) + EPSV);
    vI.y = 1.f / (sqrtf(sv.y) + EPSV);
    vI.z = 1.f / (sqrtf(sv.z) + EPSV);
    vI.w = 1.f / (sqrtf(sv.w) + EPSV);

    const int y  = y0 + ty;
    const int xb = x0 + 4 * xc;
    const float* wmRow = &smem[OFF_INVM + ty * MCOLS + 4 * xc + 3];
    float* ocB = out + (size_t)(n * 81 + iOff * RADIUS) * HW + (size_t)y * W_ + xb;

    {   // waves 0..3 store j = w
        const int j = w;
        float4 s = {0.f, 0.f, 0.f, 0.f};
#pragma unroll
        for (int g = 0; g < NW; ++g) {
            float4 v = *(const float4*)&smem[(j * 256 + g * 64 + lane) * 4];
            s.x += v.x; s.y += v.y; s.z += v.z; s.w += v.w;
        }
        float4 vd, vc;
        vd.x = s.x * vI.x; vd.y = s.y * vI.y; vd.z = s.z * vI.z; vd.w = s.w * vI.w;
        vc.x = 1.f - vd.x * wmRow[j + 0];
        vc.y = 1.f - vd.y * wmRow[j + 1];
        vc.z = 1.f - vd.z * wmRow[j + 2];
        vc.w = 1.f - vd.w * wmRow[j + 3];
        *(float4*)(ocB + (size_t)j * HW) = vc;
        *(float4*)(ocB + OUT1 + (size_t)j * HW) = vd;
    }
    __syncthreads();
#pragma unroll
    for (int q = 0; q < 5; ++q) {
        float4 v = {acc[0][q + 4], acc[1][q + 4], acc[2][q + 4], acc[3][q + 4]};
        *(float4*)&smem[(q * 256 + slot) * 4] = v;
    }
    __syncthreads();
    {   // waves 0..3 store j = 4 + w
        const int j = 4 + w;
        float4 s = {0.f, 0.f, 0.f, 0.f};
#pragma unroll
        for (int g = 0; g < NW; ++g) {
            float4 v = *(const float4*)&smem[((j - 4) * 256 + g * 64 + lane) * 4];
            s.x += v.x; s.y += v.y; s.z += v.z; s.w += v.w;
        }
        float4 vd, vc;
        vd.x = s.x * vI.x; vd.y = s.y * vI.y; vd.z = s.z * vI.z; vd.w = s.w * vI.w;
        vc.x = 1.f - vd.x * wmRow[j + 0];
        vc.y = 1.f - vd.y * wmRow[j + 1];
        vc.z = 1.f - vd.z * wmRow[j + 2];
        vc.w = 1.f - vd.w * wmRow[j + 3];
        *(float4*)(ocB + (size_t)j * HW) = vc;
        *(float4*)(ocB + OUT1 + (size_t)j * HW) = vd;
    }
    if (w == 0) {                          // wave 0 also stores j = 8
        const int j = 8;
        float4 s = {0.f, 0.f, 0.f, 0.f};
#pragma unroll
        for (int g = 0; g < NW; ++g) {
            float4 v = *(const float4*)&smem[(4 * 256 + g * 64 + lane) * 4];
            s.x += v.x; s.y += v.y; s.z += v.z; s.w += v.w;
        }
        float4 vd, vc;
        vd.x = s.x * vI.x; vd.y = s.y * vI.y; vd.z = s.z * vI.z; vd.w = s.w * vI.w;
        vc.x = 1.f - vd.x * wmRow[j + 0];
        vc.y = 1.f - vd.y * wmRow[j + 1];
        vc.z = 1.f - vd.z * wmRow[j + 2];
        vc.w = 1.f - vd.w * wmRow[j + 3];
        *(float4*)(ocB + (size_t)j * HW) = vc;
        *(float4*)(ocB + OUT1 + (size_t)j * HW) = vd;
    }
}

extern "C" void kernel_launch(void* const* d_in, const int* in_sizes, int n_in,
                              void* d_out, int out_size, void* d_ws, size_t ws_size,
                              hipStream_t stream) {
    const float* img = (const float*)d_in[0];
    const float* mp  = (const float*)d_in[1];
    float* out    = (float*)d_out;
    float* invM   = (float*)d_ws;                 // N_*HW floats
    float* strip  = invM  + N_ * HW;              // N_*C_*H_*4 floats
    float* strip2 = strip + (size_t)N_ * C_ * H_ * 4;

    norms_kernel<<<(N_ * HW / 4) / 32, 256, 0, stream>>>(mp, invM, strip, strip2);

    dim3 grid(W_ / XT, H_ / YT, N_ * RADIUS);     // 3 x 32 x 18 = 1728 blocks
    corr_kernel<<<grid, NT, 0, stream>>>(img, mp, invM, strip, strip2, out);
}